// Round 5
// baseline (346.015 us; speedup 1.0000x reference)
//
#include <hip/hip_runtime.h>
#include <cstdint>
#include <cstddef>

#define DD 512
#define TT 16384
#define CC 8192
#define SPLITC 32
#define EPS_DIV 1e-6f
#define EPS_NORM 1e-12f
#define EPS_PD 1e-6f

typedef _Float16 half8 __attribute__((ext_vector_type(8)));
typedef _Float16 half4 __attribute__((ext_vector_type(4)));
typedef float floatx4 __attribute__((ext_vector_type(4)));

// async global->LDS, 16B per lane; lds base must be wave-uniform
#define GLDS16(g, l) __builtin_amdgcn_global_load_lds( \
    (const __attribute__((address_space(1))) void*)(g), \
    (__attribute__((address_space(3))) void*)(l), 16, 0, 0)

// ---------------- split fp32 -> (hi, lo) fp16, [row][0:512]=hi [512:1024]=lo ----------------
__global__ __launch_bounds__(128) void k_split(const float* __restrict__ src,
                                               _Float16* __restrict__ dst) {
  const int row = blockIdx.x;
  const int col = threadIdx.x * 4;
  float4 v = *(const float4*)(src + (size_t)row * DD + col);
  half4 h, l;
  h.x = (_Float16)v.x; l.x = (_Float16)(v.x - (float)h.x);
  h.y = (_Float16)v.y; l.y = (_Float16)(v.y - (float)h.y);
  h.z = (_Float16)v.z; l.z = (_Float16)(v.z - (float)h.z);
  h.w = (_Float16)v.w; l.w = (_Float16)(v.w - (float)h.w);
  *(half4*)(dst + (size_t)row * 1024 + col) = h;
  *(half4*)(dst + (size_t)row * 1024 + 512 + col) = l;
}

// ---------------- fp32 [R][512] -> fp16 fragment-major ----------------
// dst[((rb*16 + t)*16 + slot)*512 + lane*8 .. +8] = (f16)src[rb*256+slot*16+(lane&15)]
//                                                        [t*32+(lane>>4)*8 .. +8]
// One (row, t) source granule = 32 fp32 = 128 B = one cache line, fully consumed.
__global__ __launch_bounds__(256) void k_cast_frag(const float* __restrict__ src,
                                                   _Float16* __restrict__ dst) {
  const int rb = blockIdx.x, t = blockIdx.y;
  const int lane = threadIdx.x & 63, s0 = threadIdx.x >> 6;  // s0: 0..3
  const int l15 = lane & 15, quad = lane >> 4;
#pragma unroll
  for (int s = 0; s < 4; ++s) {
    const int slot = s0 * 4 + s;  // 0..15
    const int row = rb * 256 + slot * 16 + l15;
    const float* p = src + (size_t)row * DD + t * 32 + quad * 8;
    float4 v0 = *(const float4*)p;
    float4 v1 = *(const float4*)(p + 4);
    half8 h;
    h[0] = (_Float16)v0.x; h[1] = (_Float16)v0.y;
    h[2] = (_Float16)v0.z; h[3] = (_Float16)v0.w;
    h[4] = (_Float16)v1.x; h[5] = (_Float16)v1.y;
    h[6] = (_Float16)v1.z; h[7] = (_Float16)v1.w;
    *(half8*)(dst + (((size_t)rb * 16 + t) * 16 + slot) * 512 + lane * 8) = h;
  }
}

// ---------------- imp = cb @ W^T via split-fp16 3-pass MFMA ----------------
__global__ __launch_bounds__(256) void k_gemm_mfma(
    const _Float16* __restrict__ cbs, const _Float16* __restrict__ Ws,
    float* __restrict__ imp) {
  __shared__ __align__(16) char smem[65536];  // A0,B0,A1,B1 @ 16KB each
  const int tid = threadIdx.x;
  const int w = tid >> 6, lane = tid & 63;
  const int quad = lane >> 4, l15 = lane & 15;
  const int wm = (w & 1) * 64, wn = (w >> 1) * 64;
  const int c0 = blockIdx.x * 128;
  const int n0 = blockIdx.y * 128;

  const int srow8 = lane >> 3;
  const int scol = ((lane & 7) ^ srow8) << 3;  // halfs, XOR-swizzled col block
  size_t arow[4], brow[4];
#pragma unroll
  for (int j = 0; j < 4; ++j) {
    arow[j] = (size_t)(c0 + j * 32 + w * 8 + srow8) * 1024 + scol;
    brow[j] = (size_t)(n0 + j * 32 + w * 8 + srow8) * 1024 + scol;
  }
  int aoff[4], boff[4];
#pragma unroll
  for (int i = 0; i < 4; ++i) {
    aoff[i] = ((wm + i * 16 + l15) * 64 + ((quad ^ (l15 & 7)) << 3)) * 2;
    boff[i] = ((wn + i * 16 + l15) * 64 + ((quad ^ (l15 & 7)) << 3)) * 2;
  }

  auto stage = [&](int buf, int ak, int bk) {
    char* ab = smem + buf * 32768;
    char* bb = ab + 16384;
#pragma unroll
    for (int j = 0; j < 4; ++j) {
      GLDS16(cbs + arow[j] + ak, (_Float16*)ab + (j * 32 + w * 8) * 64);
      GLDS16(Ws  + brow[j] + bk, (_Float16*)bb + (j * 32 + w * 8) * 64);
    }
  };

  floatx4 acc[4][4] = {};
  stage(0, 0, 0);
#pragma unroll 2
  for (int it = 0; it < 24; ++it) {   // 3 passes x 8 k-steps
    __syncthreads();
    if (it < 23) {
      const int n = it + 1;
      const int p = n >> 3, kk = n & 7;
      const int ak = ((p == 2) ? 512 : 0) + kk * 64;
      const int bk = ((p == 1) ? 512 : 0) + kk * 64;
      stage(n & 1, ak, bk);
    }
    const char* ab = smem + (it & 1) * 32768;
    const char* bb = ab + 16384;
#pragma unroll
    for (int ks = 0; ks < 2; ++ks) {
      const int kx = ks * 64;  // byte XOR for col-block +4 (rows are 128B here)
      half8 a[4], b[4];
#pragma unroll
      for (int mi = 0; mi < 4; ++mi)
        a[mi] = *(const half8*)(ab + (aoff[mi] ^ kx));
#pragma unroll
      for (int ni = 0; ni < 4; ++ni)
        b[ni] = *(const half8*)(bb + (boff[ni] ^ kx));
#pragma unroll
      for (int mi = 0; mi < 4; ++mi)
#pragma unroll
        for (int ni = 0; ni < 4; ++ni)
          acc[mi][ni] = __builtin_amdgcn_mfma_f32_16x16x32_f16(
              a[mi], b[ni], acc[mi][ni], 0, 0, 0);
    }
  }
  // C/D layout: col=lane&15, row=quad*4+reg
#pragma unroll
  for (int mi = 0; mi < 4; ++mi)
#pragma unroll
    for (int r = 0; r < 4; ++r) {
      const int c = c0 + wm + mi * 16 + quad * 4 + r;
#pragma unroll
      for (int ni = 0; ni < 4; ++ni) {
        const int d = n0 + wn + ni * 16 + l15;
        imp[(size_t)c * DD + d] = acc[mi][ni][r];
      }
    }
}

// ---------------- per-code squared norms (fp32) ----------------
__global__ __launch_bounds__(256) void k_row_norm2(
    const float* __restrict__ imp, float* __restrict__ cnorm) {
  const int lane = threadIdx.x & 63;
  const int row = blockIdx.x * 4 + (threadIdx.x >> 6);
  const float* p = imp + (size_t)row * DD + lane * 8;
  float4 a = *(const float4*)p;
  float4 b = *(const float4*)(p + 4);
  float s = a.x * a.x + a.y * a.y + a.z * a.z + a.w * a.w +
            b.x * b.x + b.y * b.y + b.z * b.z + b.w * b.w;
#pragma unroll
  for (int m = 1; m < 64; m <<= 1) s += __shfl_xor(s, m);
  if (lane == 0) cnorm[row] = s;
}

// ---------------- phase 1: fp16 hi.hi MFMA scores + per-row TOP-2 ----------------
// 256x256 tile, 8 waves (2Mx4N). ZERO-LDS main loop: both operands are loaded
// straight to VGPRs from fragment-major xA/ihB with coalesced dwordx4, register
// double-buffered (P/Q). One bare s_barrier per chunk keeps waves aligned so
// same-wr/wc waves hit L1 on shared fragments. Compiler inserts counted vmcnt.
__global__ __launch_bounds__(512, 2) void k_dist_top2(
    const _Float16* __restrict__ xA, const _Float16* __restrict__ ihB,
    const float* __restrict__ cnorm,
    float* __restrict__ bval, int* __restrict__ bidx) {
  __shared__ __align__(16) char smem[131072];  // top-2 scratch only
  const int tid = threadIdx.x;
  const int w = tid >> 6, lane = tid & 63;
  const int quad = lane >> 4, l15 = lane & 15;
  const int wr = w >> 2, wc = w & 3;  // 2 (M) x 4 (N) waves, 128x64 per wave
  const int r0 = blockIdx.x * 256;
  const int c0 = blockIdx.y * 256;

  const _Float16* gA = xA + ((size_t)blockIdx.x * 256 + wr * 8) * 512 + lane * 8;
  const _Float16* gB = ihB + ((size_t)blockIdx.y * 256 + wc * 4) * 512 + lane * 8;

  floatx4 acc[8][4] = {};
  half8 aP[8], bP[4], aQ[8], bQ[4];

#define LOADF(AR, BR, T) {                                                     \
    const _Float16* ga = gA + (size_t)(T) * 8192;                              \
    const _Float16* gb = gB + (size_t)(T) * 8192;                              \
    _Pragma("unroll")                                                          \
    for (int i = 0; i < 8; ++i) AR[i] = *(const half8*)(ga + i * 512);         \
    _Pragma("unroll")                                                          \
    for (int i = 0; i < 4; ++i) BR[i] = *(const half8*)(gb + i * 512);         \
  }
#define MMF(AR, BR) {                                                          \
    __builtin_amdgcn_s_barrier();                                              \
    __builtin_amdgcn_s_setprio(1);                                             \
    _Pragma("unroll")                                                          \
    for (int mi = 0; mi < 8; ++mi)                                             \
      _Pragma("unroll")                                                        \
      for (int ni = 0; ni < 4; ++ni)                                           \
        acc[mi][ni] = __builtin_amdgcn_mfma_f32_16x16x32_f16(                  \
            AR[mi], BR[ni], acc[mi][ni], 0, 0, 0);                             \
    __builtin_amdgcn_s_setprio(0);                                             \
    __builtin_amdgcn_sched_barrier(0);                                         \
  }

  LOADF(aP, bP, 0)
  LOADF(aQ, bQ, 1)   MMF(aP, bP)   // chunk 0
  LOADF(aP, bP, 2)   MMF(aQ, bQ)   // chunk 1
  LOADF(aQ, bQ, 3)   MMF(aP, bP)   // chunk 2
  LOADF(aP, bP, 4)   MMF(aQ, bQ)   // chunk 3
  LOADF(aQ, bQ, 5)   MMF(aP, bP)   // chunk 4
  LOADF(aP, bP, 6)   MMF(aQ, bQ)   // chunk 5
  LOADF(aQ, bQ, 7)   MMF(aP, bP)   // chunk 6
  LOADF(aP, bP, 8)   MMF(aQ, bQ)   // chunk 7
  LOADF(aQ, bQ, 9)   MMF(aP, bP)   // chunk 8
  LOADF(aP, bP, 10)  MMF(aQ, bQ)   // chunk 9
  LOADF(aQ, bQ, 11)  MMF(aP, bP)   // chunk 10
  LOADF(aP, bP, 12)  MMF(aQ, bQ)   // chunk 11
  LOADF(aQ, bQ, 13)  MMF(aP, bP)   // chunk 12
  LOADF(aP, bP, 14)  MMF(aQ, bQ)   // chunk 13
  LOADF(aQ, bQ, 15)  MMF(aP, bP)   // chunk 14
  MMF(aQ, bQ)                      // chunk 15
#undef LOADF
#undef MMF

  float cn[4];
#pragma unroll
  for (int ni = 0; ni < 4; ++ni)
    cn[ni] = cnorm[c0 + wc * 64 + ni * 16 + l15];

  // ---- per-row top-2 over the block's 256 codes ----
  __syncthreads();
  float* rv = (float*)smem;            // [256][64] values (64KB), bank-swizzled
  int* ri = (int*)(smem + 65536);      // [256][64] indices (64KB)
#pragma unroll
  for (int mi = 0; mi < 8; ++mi)
#pragma unroll
    for (int r = 0; r < 4; ++r) {
      const int row = wr * 128 + mi * 16 + quad * 4 + r;
      float bv = 3.4e38f; int bi = 0x7fffffff;
#pragma unroll
      for (int ni = 0; ni < 4; ++ni) {
        const float v = fmaf(-2.0f, acc[mi][ni][r], cn[ni]);
        const int c = c0 + wc * 64 + ni * 16 + l15;  // ascends with ni
        if (v < bv) { bv = v; bi = c; }
      }
      const int e = wc * 16 + l15;                   // 0..63
      const int g = (row & 31) ^ ((row & 4) << 2);   // mixes quad bit into bank bit4
      const int col = e ^ g;
      rv[row * 64 + col] = bv;
      ri[row * 64 + col] = bi;
    }
  __syncthreads();
  {
    const int row = tid >> 1, h = tid & 1;           // 2 threads per row
    const int g = (row & 31) ^ ((row & 4) << 2);
    float v1 = 3.4e38f, v2 = 3.4e38f;
    int i1 = 0x7fffffff, i2 = 0x7fffffff;
#pragma unroll
    for (int j = 0; j < 32; ++j) {
      const int e = h * 32 + j;
      const int col = e ^ g;
      const float v = rv[row * 64 + col];
      const int i = ri[row * 64 + col];
      if (v < v1 || (v == v1 && i < i1)) { v2 = v1; i2 = i1; v1 = v; i1 = i; }
      else if (v < v2 || (v == v2 && i < i2)) { v2 = v; i2 = i; }
    }
    const float w1 = __shfl_xor(v1, 1), w2 = __shfl_xor(v2, 1);
    const int j1 = __shfl_xor(i1, 1), j2 = __shfl_xor(i2, 1);
    if (w1 < v1 || (w1 == v1 && j1 < i1)) {
      if (v1 < w2 || (v1 == w2 && i1 < j2)) { v2 = v1; i2 = i1; }
      else { v2 = w2; i2 = j2; }
      v1 = w1; i1 = j1;
    } else if (w1 < v2 || (w1 == v2 && j1 < i2)) { v2 = w1; i2 = j1; }
    if (h == 0) {
      const size_t o = ((size_t)blockIdx.y * TT + r0 + row) * 2;
      bval[o] = v1; bval[o + 1] = v2;
      bidx[o] = i1; bidx[o + 1] = i2;
    }
  }
}

// ---------------- epilogue: butterfly top-2 merge, exact rescore, rotation ----------------
__global__ __launch_bounds__(256) void k_epilogue(
    const float* __restrict__ x, const float* __restrict__ imp,
    const float* __restrict__ cnorm,
    const float* __restrict__ bval, const int* __restrict__ bidx,
    float* __restrict__ outq, float* __restrict__ outidx,
    float* __restrict__ rloss) {
  const int lane = threadIdx.x & 63;
  const int row = blockIdx.x * 4 + (threadIdx.x >> 6);
  // lane p holds split p's sorted top-2 (p < SPLITC); butterfly merge -> global top-2
  float v1 = 3.4e38f, v2 = 3.4e38f;
  int i1 = 0x7fffffff, i2 = 0x7fffffff;
  if (lane < SPLITC) {
    const size_t o = ((size_t)lane * TT + row) * 2;
    v1 = bval[o]; v2 = bval[o + 1];
    i1 = bidx[o]; i2 = bidx[o + 1];
  }
#pragma unroll
  for (int m = 1; m < 64; m <<= 1) {
    const float w1 = __shfl_xor(v1, m), w2 = __shfl_xor(v2, m);
    const int j1 = __shfl_xor(i1, m), j2 = __shfl_xor(i2, m);
    if (w1 < v1 || (w1 == v1 && j1 < i1)) {
      if (v1 < w2 || (v1 == w2 && i1 < j2)) { v2 = v1; i2 = i1; }
      else { v2 = w2; i2 = j2; }
      v1 = w1; i1 = j1;
    } else {
      if (w1 < v2 || (w1 == v2 && j1 < i2)) { v2 = w1; i2 = j1; }
    }
  }
  // exact fp32 rescore of both candidates
  const float* xr = x + (size_t)row * DD + lane * 8;
  float e[8], qa[8], qb[8];
  *(float4*)&e[0] = *(const float4*)xr;
  *(float4*)&e[4] = *(const float4*)(xr + 4);
  const float* q1p = imp + (size_t)i1 * DD + lane * 8;
  const float* q2p = imp + (size_t)i2 * DD + lane * 8;
  *(float4*)&qa[0] = *(const float4*)q1p;
  *(float4*)&qa[4] = *(const float4*)(q1p + 4);
  *(float4*)&qb[0] = *(const float4*)q2p;
  *(float4*)&qb[4] = *(const float4*)(q2p + 4);
  float d1 = 0.f, d2 = 0.f;
#pragma unroll
  for (int k = 0; k < 8; ++k) {
    d1 = fmaf(e[k], qa[k], d1);
    d2 = fmaf(e[k], qb[k], d2);
  }
#pragma unroll
  for (int m = 1; m < 64; m <<= 1) {
    d1 += __shfl_xor(d1, m);
    d2 += __shfl_xor(d2, m);
  }
  const float s1 = fmaf(-2.0f, d1, cnorm[i1]);
  const float s2 = fmaf(-2.0f, d2, cnorm[i2]);
  const bool use2 = (s2 < s1) || (s2 == s1 && i2 < i1);
  const int idx = use2 ? i2 : i1;
  float q[8];
#pragma unroll
  for (int k = 0; k < 8; ++k) q[k] = use2 ? qb[k] : qa[k];

  float xx = 0.f, qq = 0.f, xq = 0.f, cl = 0.f;
#pragma unroll
  for (int k = 0; k < 8; ++k) {
    xx = fmaf(e[k], e[k], xx);
    qq = fmaf(q[k], q[k], qq);
    xq = fmaf(e[k], q[k], xq);
    float d = e[k] - q[k] + EPS_PD;
    cl = fmaf(d, d, cl);
  }
#pragma unroll
  for (int m = 1; m < 64; m <<= 1) {
    xx += __shfl_xor(xx, m);
    qq += __shfl_xor(qq, m);
    xq += __shfl_xor(xq, m);
    cl += __shfl_xor(cl, m);
  }
  const float nx = sqrtf(xx), nq = sqrtf(qq);
  const float dx = fmaxf(nx, EPS_DIV), dq = fmaxf(nq, EPS_DIV);
  const float uu = xx / (dx * dx);
  const float qq2 = qq / (dq * dq);
  const float uq = xq / (dx * dq);
  const float ss = uu + qq2 + 2.0f * uq;
  const float dn = fmaxf(sqrtf(ss), EPS_NORM);
  const float es = xx / dx + xq / dq;
  const float a = 2.0f * es / (dn * dn);
  const float b = 2.0f * (xx / dx);
  const float scale = nq / dx;

  float ov[8];
#pragma unroll
  for (int k = 0; k < 8; ++k) {
    const float qp = q[k] / dq;
    const float sk = e[k] / dx + qp;
    ov[k] = (e[k] - a * sk + b * qp) * scale;
  }
  float* op = outq + (size_t)row * DD + lane * 8;
  *(float4*)op = *(const float4*)&ov[0];
  *(float4*)(op + 4) = *(const float4*)&ov[4];
  if (lane == 0) {
    outidx[row] = (float)idx;
    rloss[row] = cl;
  }
}

// ---------------- final loss reduction (deterministic) ----------------
__global__ __launch_bounds__(256) void k_loss_final(
    const float* __restrict__ rloss, float* __restrict__ out) {
  __shared__ double red[256];
  const int tid = threadIdx.x;
  double s = 0.0;
  for (int i = tid; i < TT; i += 256) s += (double)rloss[i];
  red[tid] = s;
  __syncthreads();
  for (int st = 128; st > 0; st >>= 1) {
    if (tid < st) red[tid] += red[tid + st];
    __syncthreads();
  }
  if (tid == 0) out[0] = (float)(red[0] / (double)TT);
}

extern "C" void kernel_launch(void* const* d_in, const int* in_sizes, int n_in,
                              void* d_out, int out_size, void* d_ws, size_t ws_size,
                              hipStream_t stream) {
  const float* x  = (const float*)d_in[0];   // [TT, DD]
  const float* W  = (const float*)d_in[1];   // [DD, DD]
  const float* cb = (const float*)d_in[2];   // [CC, DD]
  float* out = (float*)d_out;

  // workspace layout; xA aliases cbs (cbs dead after k_gemm_mfma)
  float* imp = (float*)d_ws;                             // CC*DD fp32 (16 MiB)
  _Float16* ihB = (_Float16*)(imp + (size_t)CC * DD);    // CC*DD f16 frag-major (8 MiB)
  _Float16* cbs = ihB + (size_t)CC * DD;                 // CC*1024 f16 (16 MiB)
  _Float16* xA = cbs;                                    // TT*DD f16 frag-major (alias)
  _Float16* Ws = cbs + (size_t)CC * 1024;                // DD*1024 f16 (1 MiB)
  float* cnorm = (float*)(Ws + (size_t)DD * 1024);       // CC
  float* bval  = cnorm + CC;                             // SPLITC*TT*2 (4 MiB)
  int*   bidx  = (int*)(bval + (size_t)SPLITC * TT * 2); // 4 MiB
  float* rloss = (float*)(bidx + (size_t)SPLITC * TT * 2);

  float* out_q    = out;
  float* out_idx  = out + (size_t)TT * DD;
  float* out_loss = out_idx + TT;

  k_split<<<CC, 128, 0, stream>>>(cb, cbs);
  k_split<<<DD, 128, 0, stream>>>(W, Ws);
  k_gemm_mfma<<<dim3(CC / 128, DD / 128), 256, 0, stream>>>(cbs, Ws, imp);
  k_row_norm2<<<CC / 4, 256, 0, stream>>>(imp, cnorm);
  k_cast_frag<<<dim3(CC / 256, 16), 256, 0, stream>>>(imp, ihB);  // codes -> frag-major
  k_cast_frag<<<dim3(TT / 256, 16), 256, 0, stream>>>(x, xA);     // x -> frag-major
  k_dist_top2<<<dim3(TT / 256, CC / 256), 512, 0, stream>>>(xA, ihB, cnorm, bval, bidx);
  k_epilogue<<<TT / 4, 256, 0, stream>>>(x, imp, cnorm, bval, bidx, out_q, out_idx, rloss);
  k_loss_final<<<1, 256, 0, stream>>>(rloss, out_loss);
}

// Round 7
// 328.516 us; speedup vs baseline: 1.0533x; 1.0533x over previous
//
#include <hip/hip_runtime.h>
#include <cstdint>
#include <cstddef>

#define DD 512
#define TT 16384
#define CC 8192
#define SPLITC 32
#define EPS_DIV 1e-6f
#define EPS_NORM 1e-12f
#define EPS_PD 1e-6f

typedef _Float16 half8 __attribute__((ext_vector_type(8)));
typedef _Float16 half4 __attribute__((ext_vector_type(4)));
typedef float floatx4 __attribute__((ext_vector_type(4)));

// async global->LDS, 16B per lane; lds base must be wave-uniform,
// GLOBAL SOURCE IS PER-LANE (each lane supplies its own address).
#define GLDS16(g, l) __builtin_amdgcn_global_load_lds( \
    (const __attribute__((address_space(1))) void*)(g), \
    (__attribute__((address_space(3))) void*)(l), 16, 0, 0)

// ---------------- split fp32 -> (hi, lo) fp16, [row][0:512]=hi [512:1024]=lo ----------------
__global__ __launch_bounds__(128) void k_split(const float* __restrict__ src,
                                               _Float16* __restrict__ dst) {
  const int row = blockIdx.x;
  const int col = threadIdx.x * 4;
  float4 v = *(const float4*)(src + (size_t)row * DD + col);
  half4 h, l;
  h.x = (_Float16)v.x; l.x = (_Float16)(v.x - (float)h.x);
  h.y = (_Float16)v.y; l.y = (_Float16)(v.y - (float)h.y);
  h.z = (_Float16)v.z; l.z = (_Float16)(v.z - (float)h.z);
  h.w = (_Float16)v.w; l.w = (_Float16)(v.w - (float)h.w);
  *(half4*)(dst + (size_t)row * 1024 + col) = h;
  *(half4*)(dst + (size_t)row * 1024 + 512 + col) = l;
}

// ---------------- fp32 [R][512] -> fp16 fragment-major ----------------
// dst[((rb*16 + t)*16 + slot)*512 + lane*8 .. +8] = (f16)src[rb*256+slot*16+(lane&15)]
//                                                        [t*32+(lane>>4)*8 .. +8]
__global__ __launch_bounds__(256) void k_cast_frag(const float* __restrict__ src,
                                                   _Float16* __restrict__ dst) {
  const int rb = blockIdx.x, t = blockIdx.y;
  const int lane = threadIdx.x & 63, s0 = threadIdx.x >> 6;  // s0: 0..3
  const int l15 = lane & 15, quad = lane >> 4;
#pragma unroll
  for (int s = 0; s < 4; ++s) {
    const int slot = s0 * 4 + s;  // 0..15
    const int row = rb * 256 + slot * 16 + l15;
    const float* p = src + (size_t)row * DD + t * 32 + quad * 8;
    float4 v0 = *(const float4*)p;
    float4 v1 = *(const float4*)(p + 4);
    half8 h;
    h[0] = (_Float16)v0.x; h[1] = (_Float16)v0.y;
    h[2] = (_Float16)v0.z; h[3] = (_Float16)v0.w;
    h[4] = (_Float16)v1.x; h[5] = (_Float16)v1.y;
    h[6] = (_Float16)v1.z; h[7] = (_Float16)v1.w;
    *(half8*)(dst + (((size_t)rb * 16 + t) * 16 + slot) * 512 + lane * 8) = h;
  }
}

// ---------------- imp = cb @ W^T via split-fp16 3-pass MFMA ----------------
__global__ __launch_bounds__(256) void k_gemm_mfma(
    const _Float16* __restrict__ cbs, const _Float16* __restrict__ Ws,
    float* __restrict__ imp) {
  __shared__ __align__(16) char smem[65536];  // A0,B0,A1,B1 @ 16KB each
  const int tid = threadIdx.x;
  const int w = tid >> 6, lane = tid & 63;
  const int quad = lane >> 4, l15 = lane & 15;
  const int wm = (w & 1) * 64, wn = (w >> 1) * 64;
  const int c0 = blockIdx.x * 128;
  const int n0 = blockIdx.y * 128;

  const int srow8 = lane >> 3;
  const int scol = ((lane & 7) ^ srow8) << 3;  // halfs, XOR-swizzled col block
  size_t arow[4], brow[4];
#pragma unroll
  for (int j = 0; j < 4; ++j) {
    arow[j] = (size_t)(c0 + j * 32 + w * 8 + srow8) * 1024 + scol;
    brow[j] = (size_t)(n0 + j * 32 + w * 8 + srow8) * 1024 + scol;
  }
  int aoff[4], boff[4];
#pragma unroll
  for (int i = 0; i < 4; ++i) {
    aoff[i] = ((wm + i * 16 + l15) * 64 + ((quad ^ (l15 & 7)) << 3)) * 2;
    boff[i] = ((wn + i * 16 + l15) * 64 + ((quad ^ (l15 & 7)) << 3)) * 2;
  }

  auto stage = [&](int buf, int ak, int bk) {
    char* ab = smem + buf * 32768;
    char* bb = ab + 16384;
#pragma unroll
    for (int j = 0; j < 4; ++j) {
      GLDS16(cbs + arow[j] + ak, (_Float16*)ab + (j * 32 + w * 8) * 64);
      GLDS16(Ws  + brow[j] + bk, (_Float16*)bb + (j * 32 + w * 8) * 64);
    }
  };

  floatx4 acc[4][4] = {};
  stage(0, 0, 0);
#pragma unroll 2
  for (int it = 0; it < 24; ++it) {   // 3 passes x 8 k-steps
    __syncthreads();
    if (it < 23) {
      const int n = it + 1;
      const int p = n >> 3, kk = n & 7;
      const int ak = ((p == 2) ? 512 : 0) + kk * 64;
      const int bk = ((p == 1) ? 512 : 0) + kk * 64;
      stage(n & 1, ak, bk);
    }
    const char* ab = smem + (it & 1) * 32768;
    const char* bb = ab + 16384;
#pragma unroll
    for (int ks = 0; ks < 2; ++ks) {
      const int kx = ks * 64;  // byte XOR for col-block +4 (rows are 128B here)
      half8 a[4], b[4];
#pragma unroll
      for (int mi = 0; mi < 4; ++mi)
        a[mi] = *(const half8*)(ab + (aoff[mi] ^ kx));
#pragma unroll
      for (int ni = 0; ni < 4; ++ni)
        b[ni] = *(const half8*)(bb + (boff[ni] ^ kx));
#pragma unroll
      for (int mi = 0; mi < 4; ++mi)
#pragma unroll
        for (int ni = 0; ni < 4; ++ni)
          acc[mi][ni] = __builtin_amdgcn_mfma_f32_16x16x32_f16(
              a[mi], b[ni], acc[mi][ni], 0, 0, 0);
    }
  }
  // C/D layout: col=lane&15, row=quad*4+reg
#pragma unroll
  for (int mi = 0; mi < 4; ++mi)
#pragma unroll
    for (int r = 0; r < 4; ++r) {
      const int c = c0 + wm + mi * 16 + quad * 4 + r;
#pragma unroll
      for (int ni = 0; ni < 4; ++ni) {
        const int d = n0 + wn + ni * 16 + l15;
        imp[(size_t)c * DD + d] = acc[mi][ni][r];
      }
    }
}

// ---------------- per-code squared norms (fp32) ----------------
__global__ __launch_bounds__(256) void k_row_norm2(
    const float* __restrict__ imp, float* __restrict__ cnorm) {
  const int lane = threadIdx.x & 63;
  const int row = blockIdx.x * 4 + (threadIdx.x >> 6);
  const float* p = imp + (size_t)row * DD + lane * 8;
  float4 a = *(const float4*)p;
  float4 b = *(const float4*)(p + 4);
  float s = a.x * a.x + a.y * a.y + a.z * a.z + a.w * a.w +
            b.x * b.x + b.y * b.y + b.z * b.z + b.w * b.w;
#pragma unroll
  for (int m = 1; m < 64; m <<= 1) s += __shfl_xor(s, m);
  if (lane == 0) cnorm[row] = s;
}

// ---------------- phase 1: fp16 hi.hi MFMA scores + per-row TOP-2 ----------------
// 256x256 tile, 8 waves (2Mx4N). HYBRID ports: A (shared 4x) staged via
// global_load_lds into a 4x16KB LDS ring (frag-major chunks are contiguous ->
// linear staging with PER-LANE source = gA + lane*8; stride-1 conflict-free
// ds_read_b128); B (shared 2x) loaded direct-to-VGPR from frag-major global.
// Counted vmcnt (steady 6, never 0 mid-loop); GLDS issued post-barrier.
__global__ __launch_bounds__(512, 2) void k_dist_top2(
    const _Float16* __restrict__ xA, const _Float16* __restrict__ ihB,
    const float* __restrict__ cnorm,
    float* __restrict__ bval, int* __restrict__ bidx) {
  __shared__ __align__(16) char smem[131072];  // ring 4x16KB (A); top-2 scratch aliases
  const int tid = threadIdx.x;
  const int w = tid >> 6, lane = tid & 63;
  const int quad = lane >> 4, l15 = lane & 15;
  const int wr = w >> 2, wc = w & 3;  // 2 (M) x 4 (N) waves, 128x64 per wave
  const int r0 = blockIdx.x * 256;
  const int c0 = blockIdx.y * 256;

  // A: frag-major chunk = 16KB contiguous; wave w stages halfs [w*1024, (w+1)*1024)
  // of each chunk; PER-LANE source offset lane*8 halfs (16B) is mandatory.
  const _Float16* gA = xA + (size_t)blockIdx.x * 16 * 8192 + w * 1024 + lane * 8;
  // B: direct frag loads (wave wc reads slots wc*4+ni)
  const _Float16* gB = ihB + (size_t)blockIdx.y * 16 * 8192 + (wc * 4) * 512 + lane * 8;
  const int ldsDst = w * 2048;                      // within chunk's 16KB
  const int aBase = (wr * 8) * 1024 + lane * 16;    // + mi*1024 within chunk

  floatx4 acc[8][4] = {};
  half8 aM[8], bP[4], bQ[4];

#define STAGE_A(T) {                                                           \
    char* d = smem + ((T) & 3) * 16384 + ldsDst;                               \
    const _Float16* g = gA + (size_t)(T) * 8192;                               \
    GLDS16(g, d);                                                              \
    GLDS16(g + 512, d + 1024);                                                 \
  }
#define LOAD_B(BR, T) {                                                        \
    const _Float16* g = gB + (size_t)(T) * 8192;                               \
    _Pragma("unroll")                                                          \
    for (int i = 0; i < 4; ++i) BR[i] = *(const half8*)(g + i * 512);          \
  }

// per chunk: ds_read A(t) + load B(t+1) pre-barrier; counted vmcnt retires own
// B(t) and G(t+1) pre-barrier; barrier; lgkm drain; GLDS A(t+3) post-barrier
// (latency hides under MFMA burst, needed 2.5 chunks later); 32 MFMA.
#define CHUNK(T, BCUR, BNXT, DO_B, DO_G, VMC) {                                \
    const char* bb = smem + ((T) & 3) * 16384;                                 \
    _Pragma("unroll")                                                          \
    for (int i = 0; i < 8; ++i)                                                \
      aM[i] = *(const half8*)(bb + aBase + i * 1024);                          \
    if (DO_B) LOAD_B(BNXT, (T) + 1)                                            \
    asm volatile("s_waitcnt vmcnt(" #VMC ")" ::: "memory");                    \
    __builtin_amdgcn_s_barrier();                                              \
    asm volatile("s_waitcnt lgkmcnt(0)" ::: "memory");                         \
    __builtin_amdgcn_sched_barrier(0);                                         \
    if (DO_G) STAGE_A((T) + 3)                                                 \
    __builtin_amdgcn_s_setprio(1);                                             \
    _Pragma("unroll")                                                          \
    for (int mi = 0; mi < 8; ++mi)                                             \
      _Pragma("unroll")                                                        \
      for (int ni = 0; ni < 4; ++ni)                                           \
        acc[mi][ni] = __builtin_amdgcn_mfma_f32_16x16x32_f16(                  \
            aM[mi], BCUR[ni], acc[mi][ni], 0, 0, 0);                           \
    __builtin_amdgcn_s_setprio(0);                                             \
    __builtin_amdgcn_sched_barrier(0);                                         \
  }

  // prologue: stage A chunks 0..2 (6 GLDS), load B(0); retire own G(0); barrier
  STAGE_A(0) STAGE_A(1) STAGE_A(2)
  LOAD_B(bP, 0)
  asm volatile("s_waitcnt vmcnt(8)" ::: "memory");
  __builtin_amdgcn_s_barrier();
  __builtin_amdgcn_sched_barrier(0);

  CHUNK(0,  bP, bQ, 1, 1, 4)
  CHUNK(1,  bQ, bP, 1, 1, 6)
  CHUNK(2,  bP, bQ, 1, 1, 6)
  CHUNK(3,  bQ, bP, 1, 1, 6)
  CHUNK(4,  bP, bQ, 1, 1, 6)
  CHUNK(5,  bQ, bP, 1, 1, 6)
  CHUNK(6,  bP, bQ, 1, 1, 6)
  CHUNK(7,  bQ, bP, 1, 1, 6)
  CHUNK(8,  bP, bQ, 1, 1, 6)
  CHUNK(9,  bQ, bP, 1, 1, 6)
  CHUNK(10, bP, bQ, 1, 1, 6)
  CHUNK(11, bQ, bP, 1, 1, 6)
  CHUNK(12, bP, bQ, 1, 1, 6)
  CHUNK(13, bQ, bP, 1, 0, 6)
  CHUNK(14, bP, bQ, 1, 0, 4)
  CHUNK(15, bQ, bP, 0, 0, 0)
#undef CHUNK
#undef STAGE_A
#undef LOAD_B

  float cn[4];
#pragma unroll
  for (int ni = 0; ni < 4; ++ni)
    cn[ni] = cnorm[c0 + wc * 64 + ni * 16 + l15];

  // ---- per-row top-2 over the block's 256 codes ----
  __syncthreads();
  float* rv = (float*)smem;            // [256][64] values (64KB), bank-swizzled
  int* ri = (int*)(smem + 65536);      // [256][64] indices (64KB)
#pragma unroll
  for (int mi = 0; mi < 8; ++mi)
#pragma unroll
    for (int r = 0; r < 4; ++r) {
      const int row = wr * 128 + mi * 16 + quad * 4 + r;
      float bv = 3.4e38f; int bi = 0x7fffffff;
#pragma unroll
      for (int ni = 0; ni < 4; ++ni) {
        const float v = fmaf(-2.0f, acc[mi][ni][r], cn[ni]);
        const int c = c0 + wc * 64 + ni * 16 + l15;  // ascends with ni
        if (v < bv) { bv = v; bi = c; }
      }
      const int e = wc * 16 + l15;                   // 0..63
      const int g = (row & 31) ^ ((row & 4) << 2);   // mixes quad bit into bank bit4
      const int col = e ^ g;
      rv[row * 64 + col] = bv;
      ri[row * 64 + col] = bi;
    }
  __syncthreads();
  {
    const int row = tid >> 1, h = tid & 1;           // 2 threads per row
    const int g = (row & 31) ^ ((row & 4) << 2);
    float v1 = 3.4e38f, v2 = 3.4e38f;
    int i1 = 0x7fffffff, i2 = 0x7fffffff;
#pragma unroll
    for (int j = 0; j < 32; ++j) {
      const int e = h * 32 + j;
      const int col = e ^ g;
      const float v = rv[row * 64 + col];
      const int i = ri[row * 64 + col];
      if (v < v1 || (v == v1 && i < i1)) { v2 = v1; i2 = i1; v1 = v; i1 = i; }
      else if (v < v2 || (v == v2 && i < i2)) { v2 = v; i2 = i; }
    }
    const float w1 = __shfl_xor(v1, 1), w2 = __shfl_xor(v2, 1);
    const int j1 = __shfl_xor(i1, 1), j2 = __shfl_xor(i2, 1);
    if (w1 < v1 || (w1 == v1 && j1 < i1)) {
      if (v1 < w2 || (v1 == w2 && i1 < j2)) { v2 = v1; i2 = i1; }
      else { v2 = w2; i2 = j2; }
      v1 = w1; i1 = j1;
    } else if (w1 < v2 || (w1 == v2 && j1 < i2)) { v2 = w1; i2 = j1; }
    if (h == 0) {
      const size_t o = ((size_t)blockIdx.y * TT + r0 + row) * 2;
      bval[o] = v1; bval[o + 1] = v2;
      bidx[o] = i1; bidx[o + 1] = i2;
    }
  }
}

// ---------------- epilogue: butterfly top-2 merge, exact rescore, rotation ----------------
__global__ __launch_bounds__(256) void k_epilogue(
    const float* __restrict__ x, const float* __restrict__ imp,
    const float* __restrict__ cnorm,
    const float* __restrict__ bval, const int* __restrict__ bidx,
    float* __restrict__ outq, float* __restrict__ outidx,
    float* __restrict__ rloss) {
  const int lane = threadIdx.x & 63;
  const int row = blockIdx.x * 4 + (threadIdx.x >> 6);
  // lane p holds split p's sorted top-2 (p < SPLITC); butterfly merge -> global top-2
  float v1 = 3.4e38f, v2 = 3.4e38f;
  int i1 = 0x7fffffff, i2 = 0x7fffffff;
  if (lane < SPLITC) {
    const size_t o = ((size_t)lane * TT + row) * 2;
    v1 = bval[o]; v2 = bval[o + 1];
    i1 = bidx[o]; i2 = bidx[o + 1];
  }
#pragma unroll
  for (int m = 1; m < 64; m <<= 1) {
    const float w1 = __shfl_xor(v1, m), w2 = __shfl_xor(v2, m);
    const int j1 = __shfl_xor(i1, m), j2 = __shfl_xor(i2, m);
    if (w1 < v1 || (w1 == v1 && j1 < i1)) {
      if (v1 < w2 || (v1 == w2 && i1 < j2)) { v2 = v1; i2 = i1; }
      else { v2 = w2; i2 = j2; }
      v1 = w1; i1 = j1;
    } else {
      if (w1 < v2 || (w1 == v2 && j1 < i2)) { v2 = w1; i2 = j1; }
    }
  }
  // exact fp32 rescore of both candidates
  const float* xr = x + (size_t)row * DD + lane * 8;
  float e[8], qa[8], qb[8];
  *(float4*)&e[0] = *(const float4*)xr;
  *(float4*)&e[4] = *(const float4*)(xr + 4);
  const float* q1p = imp + (size_t)i1 * DD + lane * 8;
  const float* q2p = imp + (size_t)i2 * DD + lane * 8;
  *(float4*)&qa[0] = *(const float4*)q1p;
  *(float4*)&qa[4] = *(const float4*)(q1p + 4);
  *(float4*)&qb[0] = *(const float4*)q2p;
  *(float4*)&qb[4] = *(const float4*)(q2p + 4);
  float d1 = 0.f, d2 = 0.f;
#pragma unroll
  for (int k = 0; k < 8; ++k) {
    d1 = fmaf(e[k], qa[k], d1);
    d2 = fmaf(e[k], qb[k], d2);
  }
#pragma unroll
  for (int m = 1; m < 64; m <<= 1) {
    d1 += __shfl_xor(d1, m);
    d2 += __shfl_xor(d2, m);
  }
  const float s1 = fmaf(-2.0f, d1, cnorm[i1]);
  const float s2 = fmaf(-2.0f, d2, cnorm[i2]);
  const bool use2 = (s2 < s1) || (s2 == s1 && i2 < i1);
  const int idx = use2 ? i2 : i1;
  float q[8];
#pragma unroll
  for (int k = 0; k < 8; ++k) q[k] = use2 ? qb[k] : qa[k];

  float xx = 0.f, qq = 0.f, xq = 0.f, cl = 0.f;
#pragma unroll
  for (int k = 0; k < 8; ++k) {
    xx = fmaf(e[k], e[k], xx);
    qq = fmaf(q[k], q[k], qq);
    xq = fmaf(e[k], q[k], xq);
    float d = e[k] - q[k] + EPS_PD;
    cl = fmaf(d, d, cl);
  }
#pragma unroll
  for (int m = 1; m < 64; m <<= 1) {
    xx += __shfl_xor(xx, m);
    qq += __shfl_xor(qq, m);
    xq += __shfl_xor(xq, m);
    cl += __shfl_xor(cl, m);
  }
  const float nx = sqrtf(xx), nq = sqrtf(qq);
  const float dx = fmaxf(nx, EPS_DIV), dq = fmaxf(nq, EPS_DIV);
  const float uu = xx / (dx * dx);
  const float qq2 = qq / (dq * dq);
  const float uq = xq / (dx * dq);
  const float ss = uu + qq2 + 2.0f * uq;
  const float dn = fmaxf(sqrtf(ss), EPS_NORM);
  const float es = xx / dx + xq / dq;
  const float a = 2.0f * es / (dn * dn);
  const float b = 2.0f * (xx / dx);
  const float scale = nq / dx;

  float ov[8];
#pragma unroll
  for (int k = 0; k < 8; ++k) {
    const float qp = q[k] / dq;
    const float sk = e[k] / dx + qp;
    ov[k] = (e[k] - a * sk + b * qp) * scale;
  }
  float* op = outq + (size_t)row * DD + lane * 8;
  *(float4*)op = *(const float4*)&ov[0];
  *(float4*)(op + 4) = *(const float4*)&ov[4];
  if (lane == 0) {
    outidx[row] = (float)idx;
    rloss[row] = cl;
  }
}

// ---------------- final loss reduction (deterministic) ----------------
__global__ __launch_bounds__(256) void k_loss_final(
    const float* __restrict__ rloss, float* __restrict__ out) {
  __shared__ double red[256];
  const int tid = threadIdx.x;
  double s = 0.0;
  for (int i = tid; i < TT; i += 256) s += (double)rloss[i];
  red[tid] = s;
  __syncthreads();
  for (int st = 128; st > 0; st >>= 1) {
    if (tid < st) red[tid] += red[tid + st];
    __syncthreads();
  }
  if (tid == 0) out[0] = (float)(red[0] / (double)TT);
}

extern "C" void kernel_launch(void* const* d_in, const int* in_sizes, int n_in,
                              void* d_out, int out_size, void* d_ws, size_t ws_size,
                              hipStream_t stream) {
  const float* x  = (const float*)d_in[0];   // [TT, DD]
  const float* W  = (const float*)d_in[1];   // [DD, DD]
  const float* cb = (const float*)d_in[2];   // [CC, DD]
  float* out = (float*)d_out;

  // workspace layout; xA aliases cbs (cbs dead after k_gemm_mfma)
  float* imp = (float*)d_ws;                             // CC*DD fp32 (16 MiB)
  _Float16* ihB = (_Float16*)(imp + (size_t)CC * DD);    // CC*DD f16 frag-major (8 MiB)
  _Float16* cbs = ihB + (size_t)CC * DD;                 // CC*1024 f16 (16 MiB)
  _Float16* xA = cbs;                                    // TT*DD f16 frag-major (alias)
  _Float16* Ws = cbs + (size_t)CC * 1024;                // DD*1024 f16 (1 MiB)
  float* cnorm = (float*)(Ws + (size_t)DD * 1024);       // CC
  float* bval  = cnorm + CC;                             // SPLITC*TT*2 (4 MiB)
  int*   bidx  = (int*)(bval + (size_t)SPLITC * TT * 2); // 4 MiB
  float* rloss = (float*)(bidx + (size_t)SPLITC * TT * 2);

  float* out_q    = out;
  float* out_idx  = out + (size_t)TT * DD;
  float* out_loss = out_idx + TT;

  k_split<<<CC, 128, 0, stream>>>(cb, cbs);
  k_split<<<DD, 128, 0, stream>>>(W, Ws);
  k_gemm_mfma<<<dim3(CC / 128, DD / 128), 256, 0, stream>>>(cbs, Ws, imp);
  k_row_norm2<<<CC / 4, 256, 0, stream>>>(imp, cnorm);
  k_cast_frag<<<dim3(CC / 256, 16), 256, 0, stream>>>(imp, ihB);  // codes -> frag-major
  k_cast_frag<<<dim3(TT / 256, 16), 256, 0, stream>>>(x, xA);     // x -> frag-major
  k_dist_top2<<<dim3(TT / 256, CC / 256), 512, 0, stream>>>(xA, ihB, cnorm, bval, bidx);
  k_epilogue<<<TT / 4, 256, 0, stream>>>(x, imp, cnorm, bval, bidx, out_q, out_idx, rloss);
  k_loss_final<<<1, 256, 0, stream>>>(rloss, out_loss);
}

// Round 8
// 313.850 us; speedup vs baseline: 1.1025x; 1.0467x over previous
//
#include <hip/hip_runtime.h>
#include <cstdint>
#include <cstddef>

#define DD 512
#define TT 16384
#define CC 8192
#define SPLITC 64
#define EPS_DIV 1e-6f
#define EPS_NORM 1e-12f
#define EPS_PD 1e-6f

typedef _Float16 half8 __attribute__((ext_vector_type(8)));
typedef _Float16 half4 __attribute__((ext_vector_type(4)));
typedef float floatx4 __attribute__((ext_vector_type(4)));

// async global->LDS, 16B per lane; lds base must be wave-uniform,
// GLOBAL SOURCE IS PER-LANE (each lane supplies its own address).
#define GLDS16(g, l) __builtin_amdgcn_global_load_lds( \
    (const __attribute__((address_space(1))) void*)(g), \
    (__attribute__((address_space(3))) void*)(l), 16, 0, 0)

// ---------------- split fp32 -> (hi, lo) fp16, [row][0:512]=hi [512:1024]=lo ----------------
__global__ __launch_bounds__(128) void k_split(const float* __restrict__ src,
                                               _Float16* __restrict__ dst) {
  const int row = blockIdx.x;
  const int col = threadIdx.x * 4;
  float4 v = *(const float4*)(src + (size_t)row * DD + col);
  half4 h, l;
  h.x = (_Float16)v.x; l.x = (_Float16)(v.x - (float)h.x);
  h.y = (_Float16)v.y; l.y = (_Float16)(v.y - (float)h.y);
  h.z = (_Float16)v.z; l.z = (_Float16)(v.z - (float)h.z);
  h.w = (_Float16)v.w; l.w = (_Float16)(v.w - (float)h.w);
  *(half4*)(dst + (size_t)row * 1024 + col) = h;
  *(half4*)(dst + (size_t)row * 1024 + 512 + col) = l;
}

// ---------------- fp32 [R][512] -> fp16 fragment-major ----------------
// dst[((rb*16 + t)*16 + slot)*512 + lane*8 .. +8] = (f16)src[rb*256+slot*16+(lane&15)]
//                                                        [t*32+(lane>>4)*8 .. +8]
__global__ __launch_bounds__(256) void k_cast_frag(const float* __restrict__ src,
                                                   _Float16* __restrict__ dst) {
  const int rb = blockIdx.x, t = blockIdx.y;
  const int lane = threadIdx.x & 63, s0 = threadIdx.x >> 6;  // s0: 0..3
  const int l15 = lane & 15, quad = lane >> 4;
#pragma unroll
  for (int s = 0; s < 4; ++s) {
    const int slot = s0 * 4 + s;  // 0..15
    const int row = rb * 256 + slot * 16 + l15;
    const float* p = src + (size_t)row * DD + t * 32 + quad * 8;
    float4 v0 = *(const float4*)p;
    float4 v1 = *(const float4*)(p + 4);
    half8 h;
    h[0] = (_Float16)v0.x; h[1] = (_Float16)v0.y;
    h[2] = (_Float16)v0.z; h[3] = (_Float16)v0.w;
    h[4] = (_Float16)v1.x; h[5] = (_Float16)v1.y;
    h[6] = (_Float16)v1.z; h[7] = (_Float16)v1.w;
    *(half8*)(dst + (((size_t)rb * 16 + t) * 16 + slot) * 512 + lane * 8) = h;
  }
}

// ---------------- imp = cb @ W^T via split-fp16 3-pass MFMA ----------------
__global__ __launch_bounds__(256) void k_gemm_mfma(
    const _Float16* __restrict__ cbs, const _Float16* __restrict__ Ws,
    float* __restrict__ imp) {
  __shared__ __align__(16) char smem[65536];  // A0,B0,A1,B1 @ 16KB each
  const int tid = threadIdx.x;
  const int w = tid >> 6, lane = tid & 63;
  const int quad = lane >> 4, l15 = lane & 15;
  const int wm = (w & 1) * 64, wn = (w >> 1) * 64;
  const int c0 = blockIdx.x * 128;
  const int n0 = blockIdx.y * 128;

  const int srow8 = lane >> 3;
  const int scol = ((lane & 7) ^ srow8) << 3;  // halfs, XOR-swizzled col block
  size_t arow[4], brow[4];
#pragma unroll
  for (int j = 0; j < 4; ++j) {
    arow[j] = (size_t)(c0 + j * 32 + w * 8 + srow8) * 1024 + scol;
    brow[j] = (size_t)(n0 + j * 32 + w * 8 + srow8) * 1024 + scol;
  }
  int aoff[4], boff[4];
#pragma unroll
  for (int i = 0; i < 4; ++i) {
    aoff[i] = ((wm + i * 16 + l15) * 64 + ((quad ^ (l15 & 7)) << 3)) * 2;
    boff[i] = ((wn + i * 16 + l15) * 64 + ((quad ^ (l15 & 7)) << 3)) * 2;
  }

  auto stage = [&](int buf, int ak, int bk) {
    char* ab = smem + buf * 32768;
    char* bb = ab + 16384;
#pragma unroll
    for (int j = 0; j < 4; ++j) {
      GLDS16(cbs + arow[j] + ak, (_Float16*)ab + (j * 32 + w * 8) * 64);
      GLDS16(Ws  + brow[j] + bk, (_Float16*)bb + (j * 32 + w * 8) * 64);
    }
  };

  floatx4 acc[4][4] = {};
  stage(0, 0, 0);
#pragma unroll 2
  for (int it = 0; it < 24; ++it) {   // 3 passes x 8 k-steps
    __syncthreads();
    if (it < 23) {
      const int n = it + 1;
      const int p = n >> 3, kk = n & 7;
      const int ak = ((p == 2) ? 512 : 0) + kk * 64;
      const int bk = ((p == 1) ? 512 : 0) + kk * 64;
      stage(n & 1, ak, bk);
    }
    const char* ab = smem + (it & 1) * 32768;
    const char* bb = ab + 16384;
#pragma unroll
    for (int ks = 0; ks < 2; ++ks) {
      const int kx = ks * 64;  // byte XOR for col-block +4 (rows are 128B here)
      half8 a[4], b[4];
#pragma unroll
      for (int mi = 0; mi < 4; ++mi)
        a[mi] = *(const half8*)(ab + (aoff[mi] ^ kx));
#pragma unroll
      for (int ni = 0; ni < 4; ++ni)
        b[ni] = *(const half8*)(bb + (boff[ni] ^ kx));
#pragma unroll
      for (int mi = 0; mi < 4; ++mi)
#pragma unroll
        for (int ni = 0; ni < 4; ++ni)
          acc[mi][ni] = __builtin_amdgcn_mfma_f32_16x16x32_f16(
              a[mi], b[ni], acc[mi][ni], 0, 0, 0);
    }
  }
  // C/D layout: col=lane&15, row=quad*4+reg
#pragma unroll
  for (int mi = 0; mi < 4; ++mi)
#pragma unroll
    for (int r = 0; r < 4; ++r) {
      const int c = c0 + wm + mi * 16 + quad * 4 + r;
#pragma unroll
      for (int ni = 0; ni < 4; ++ni) {
        const int d = n0 + wn + ni * 16 + l15;
        imp[(size_t)c * DD + d] = acc[mi][ni][r];
      }
    }
}

// ---------------- per-code squared norms (fp32) ----------------
__global__ __launch_bounds__(256) void k_row_norm2(
    const float* __restrict__ imp, float* __restrict__ cnorm) {
  const int lane = threadIdx.x & 63;
  const int row = blockIdx.x * 4 + (threadIdx.x >> 6);
  const float* p = imp + (size_t)row * DD + lane * 8;
  float4 a = *(const float4*)p;
  float4 b = *(const float4*)(p + 4);
  float s = a.x * a.x + a.y * a.y + a.z * a.z + a.w * a.w +
            b.x * b.x + b.y * b.y + b.z * b.z + b.w * b.w;
#pragma unroll
  for (int m = 1; m < 64; m <<= 1) s += __shfl_xor(s, m);
  if (lane == 0) cnorm[row] = s;
}

// ---------------- phase 1: fp16 hi.hi MFMA scores + per-row TOP-2 ----------------
// 128x128 tile, 4 waves (2Mx2N, 64x64/wave), hybrid ports (A via GLDS ring
// 4x8KB + linear ds_read; B direct-to-VGPR frag-major), counted vmcnt (steady
// 6, never 0 mid-loop). Small LDS (33KB) + launch_bounds(256,3) -> 3-4
// INDEPENDENT blocks/CU so collective stalls of one block hide under another's
// MFMA. XCD-aware bijective decompose: each XCD owns a 16-wide bx range so its
// A panel (2MB) stays L2-resident.
__global__ __launch_bounds__(256, 3) void k_dist_top2(
    const _Float16* __restrict__ xA, const _Float16* __restrict__ ihB,
    const float* __restrict__ cnorm,
    float* __restrict__ bval, int* __restrict__ bidx) {
  __shared__ __align__(16) char smem[33792];  // ring 4x8KB; top-2 scratch aliases
  const int tid = threadIdx.x;
  const int w = tid >> 6, lane = tid & 63;
  const int quad = lane >> 4, l15 = lane & 15;
  const int wr = w >> 1, wc = w & 1;  // 2 (M) x 2 (N) waves
  const int bid = blockIdx.x;
  const int bx = (bid & 7) * 16 + ((bid >> 3) & 15);  // row tile 0..127 (per-XCD x-chunk)
  const int by = bid >> 7;                            // code tile 0..63
  const int r0 = bx * 128;
  const int c0 = by * 128;

  // frag-major: 256-row blocks of 16 chunks x 16 slots x 512 halfs.
  // bx covers slots [(bx&1)*8, +8) of rb=bx>>1 -> 4096-half contiguous region/chunk.
  const _Float16* gA = xA + (size_t)(bx >> 1) * 131072 + (bx & 1) * 4096
                          + w * 1024 + lane * 8;   // per-lane source (mandatory)
  const _Float16* gB = ihB + (size_t)(by >> 1) * 131072 + (by & 1) * 4096
                          + (wc * 4) * 512 + lane * 8;
  const int ldsDst = w * 2048;                    // bytes within chunk's 8KB
  const int aBase = (wr * 4) * 1024 + lane * 16;  // + mi*1024 within chunk

  floatx4 acc[4][4] = {};
  half8 aM[4], bP[4], bQ[4];

#define STAGE_A(T) {                                                           \
    char* d = smem + ((T) & 3) * 8192 + ldsDst;                                \
    const _Float16* g = gA + (size_t)(T) * 8192;                               \
    GLDS16(g, d);                                                              \
    GLDS16(g + 512, d + 1024);                                                 \
  }
#define LOAD_B(BR, T) {                                                        \
    const _Float16* g = gB + (size_t)(T) * 8192;                               \
    _Pragma("unroll")                                                          \
    for (int i = 0; i < 4; ++i) BR[i] = *(const half8*)(g + i * 512);          \
  }

// per chunk: ds_read A(t) + load B(t+1) pre-barrier; counted vmcnt retires own
// B(t) and G(t+1) pre-barrier; barrier; lgkm drain; GLDS A(t+3) post-barrier;
// 16 MFMA. (6 VM ops/chunk/wave -> same vmcnt accounting as verified round 7.)
#define CHUNK(T, BCUR, BNXT, DO_B, DO_G, VMC) {                                \
    const char* bb = smem + ((T) & 3) * 8192;                                  \
    _Pragma("unroll")                                                          \
    for (int i = 0; i < 4; ++i)                                                \
      aM[i] = *(const half8*)(bb + aBase + i * 1024);                          \
    if (DO_B) LOAD_B(BNXT, (T) + 1)                                            \
    asm volatile("s_waitcnt vmcnt(" #VMC ")" ::: "memory");                    \
    __builtin_amdgcn_s_barrier();                                              \
    asm volatile("s_waitcnt lgkmcnt(0)" ::: "memory");                         \
    __builtin_amdgcn_sched_barrier(0);                                         \
    if (DO_G) STAGE_A((T) + 3)                                                 \
    __builtin_amdgcn_s_setprio(1);                                             \
    _Pragma("unroll")                                                          \
    for (int mi = 0; mi < 4; ++mi)                                             \
      _Pragma("unroll")                                                        \
      for (int ni = 0; ni < 4; ++ni)                                           \
        acc[mi][ni] = __builtin_amdgcn_mfma_f32_16x16x32_f16(                  \
            aM[mi], BCUR[ni], acc[mi][ni], 0, 0, 0);                           \
    __builtin_amdgcn_s_setprio(0);                                             \
    __builtin_amdgcn_sched_barrier(0);                                         \
  }

  // prologue: stage A chunks 0..2 (6 GLDS), load B(0); retire own G(0); barrier
  STAGE_A(0) STAGE_A(1) STAGE_A(2)
  LOAD_B(bP, 0)
  asm volatile("s_waitcnt vmcnt(8)" ::: "memory");
  __builtin_amdgcn_s_barrier();
  __builtin_amdgcn_sched_barrier(0);

  CHUNK(0,  bP, bQ, 1, 1, 4)
  CHUNK(1,  bQ, bP, 1, 1, 6)
  CHUNK(2,  bP, bQ, 1, 1, 6)
  CHUNK(3,  bQ, bP, 1, 1, 6)
  CHUNK(4,  bP, bQ, 1, 1, 6)
  CHUNK(5,  bQ, bP, 1, 1, 6)
  CHUNK(6,  bP, bQ, 1, 1, 6)
  CHUNK(7,  bQ, bP, 1, 1, 6)
  CHUNK(8,  bP, bQ, 1, 1, 6)
  CHUNK(9,  bQ, bP, 1, 1, 6)
  CHUNK(10, bP, bQ, 1, 1, 6)
  CHUNK(11, bQ, bP, 1, 1, 6)
  CHUNK(12, bP, bQ, 1, 1, 6)
  CHUNK(13, bQ, bP, 1, 0, 6)
  CHUNK(14, bP, bQ, 1, 0, 4)
  CHUNK(15, bQ, bP, 0, 0, 0)
#undef CHUNK
#undef STAGE_A
#undef LOAD_B

  float cn[4];
#pragma unroll
  for (int ni = 0; ni < 4; ++ni)
    cn[ni] = cnorm[c0 + wc * 64 + ni * 16 + l15];

  // ---- per-row top-2 over the block's 128 codes ----
  __syncthreads();
  float* rv = (float*)smem;            // [128][33] (+1 pad spreads banks)
  int* ri = (int*)(smem + 16896);      // [128][33]
#pragma unroll
  for (int mi = 0; mi < 4; ++mi)
#pragma unroll
    for (int r = 0; r < 4; ++r) {
      const int row = wr * 64 + mi * 16 + quad * 4 + r;
      float bv = 3.4e38f; int bi = 0x7fffffff;
#pragma unroll
      for (int ni = 0; ni < 4; ++ni) {
        const float v = fmaf(-2.0f, acc[mi][ni][r], cn[ni]);
        const int c = c0 + wc * 64 + ni * 16 + l15;  // ascends with ni
        if (v < bv) { bv = v; bi = c; }
      }
      const int e = wc * 16 + l15;                   // 0..31
      rv[row * 33 + e] = bv;
      ri[row * 33 + e] = bi;
    }
  __syncthreads();
  {
    const int row = tid >> 1, h = tid & 1;           // 2 threads per row
    float v1 = 3.4e38f, v2 = 3.4e38f;
    int i1 = 0x7fffffff, i2 = 0x7fffffff;
#pragma unroll
    for (int j = 0; j < 16; ++j) {
      const int e = h * 16 + j;
      const float v = rv[row * 33 + e];
      const int i = ri[row * 33 + e];
      if (v < v1 || (v == v1 && i < i1)) { v2 = v1; i2 = i1; v1 = v; i1 = i; }
      else if (v < v2 || (v == v2 && i < i2)) { v2 = v; i2 = i; }
    }
    const float w1 = __shfl_xor(v1, 1), w2 = __shfl_xor(v2, 1);
    const int j1 = __shfl_xor(i1, 1), j2 = __shfl_xor(i2, 1);
    if (w1 < v1 || (w1 == v1 && j1 < i1)) {
      if (v1 < w2 || (v1 == w2 && i1 < j2)) { v2 = v1; i2 = i1; }
      else { v2 = w2; i2 = j2; }
      v1 = w1; i1 = j1;
    } else if (w1 < v2 || (w1 == v2 && j1 < i2)) { v2 = w1; i2 = j1; }
    if (h == 0) {
      const size_t o = ((size_t)by * TT + r0 + row) * 2;
      bval[o] = v1; bval[o + 1] = v2;
      bidx[o] = i1; bidx[o + 1] = i2;
    }
  }
}

// ---------------- epilogue: butterfly top-2 merge, exact rescore, rotation ----------------
__global__ __launch_bounds__(256) void k_epilogue(
    const float* __restrict__ x, const float* __restrict__ imp,
    const float* __restrict__ cnorm,
    const float* __restrict__ bval, const int* __restrict__ bidx,
    float* __restrict__ outq, float* __restrict__ outidx,
    float* __restrict__ rloss) {
  const int lane = threadIdx.x & 63;
  const int row = blockIdx.x * 4 + (threadIdx.x >> 6);
  // lane p holds split p's sorted top-2 (SPLITC=64); butterfly merge -> global top-2
  const size_t o = ((size_t)lane * TT + row) * 2;
  float v1 = bval[o], v2 = bval[o + 1];
  int i1 = bidx[o], i2 = bidx[o + 1];
#pragma unroll
  for (int m = 1; m < 64; m <<= 1) {
    const float w1 = __shfl_xor(v1, m), w2 = __shfl_xor(v2, m);
    const int j1 = __shfl_xor(i1, m), j2 = __shfl_xor(i2, m);
    if (w1 < v1 || (w1 == v1 && j1 < i1)) {
      if (v1 < w2 || (v1 == w2 && i1 < j2)) { v2 = v1; i2 = i1; }
      else { v2 = w2; i2 = j2; }
      v1 = w1; i1 = j1;
    } else {
      if (w1 < v2 || (w1 == v2 && j1 < i2)) { v2 = w1; i2 = j1; }
    }
  }
  // exact fp32 rescore of both candidates
  const float* xr = x + (size_t)row * DD + lane * 8;
  float e[8], qa[8], qb[8];
  *(float4*)&e[0] = *(const float4*)xr;
  *(float4*)&e[4] = *(const float4*)(xr + 4);
  const float* q1p = imp + (size_t)i1 * DD + lane * 8;
  const float* q2p = imp + (size_t)i2 * DD + lane * 8;
  *(float4*)&qa[0] = *(const float4*)q1p;
  *(float4*)&qa[4] = *(const float4*)(q1p + 4);
  *(float4*)&qb[0] = *(const float4*)q2p;
  *(float4*)&qb[4] = *(const float4*)(q2p + 4);
  float d1 = 0.f, d2 = 0.f;
#pragma unroll
  for (int k = 0; k < 8; ++k) {
    d1 = fmaf(e[k], qa[k], d1);
    d2 = fmaf(e[k], qb[k], d2);
  }
#pragma unroll
  for (int m = 1; m < 64; m <<= 1) {
    d1 += __shfl_xor(d1, m);
    d2 += __shfl_xor(d2, m);
  }
  const float s1 = fmaf(-2.0f, d1, cnorm[i1]);
  const float s2 = fmaf(-2.0f, d2, cnorm[i2]);
  const bool use2 = (s2 < s1) || (s2 == s1 && i2 < i1);
  const int idx = use2 ? i2 : i1;
  float q[8];
#pragma unroll
  for (int k = 0; k < 8; ++k) q[k] = use2 ? qb[k] : qa[k];

  float xx = 0.f, qq = 0.f, xq = 0.f, cl = 0.f;
#pragma unroll
  for (int k = 0; k < 8; ++k) {
    xx = fmaf(e[k], e[k], xx);
    qq = fmaf(q[k], q[k], qq);
    xq = fmaf(e[k], q[k], xq);
    float d = e[k] - q[k] + EPS_PD;
    cl = fmaf(d, d, cl);
  }
#pragma unroll
  for (int m = 1; m < 64; m <<= 1) {
    xx += __shfl_xor(xx, m);
    qq += __shfl_xor(qq, m);
    xq += __shfl_xor(xq, m);
    cl += __shfl_xor(cl, m);
  }
  const float nx = sqrtf(xx), nq = sqrtf(qq);
  const float dx = fmaxf(nx, EPS_DIV), dq = fmaxf(nq, EPS_DIV);
  const float uu = xx / (dx * dx);
  const float qq2 = qq / (dq * dq);
  const float uq = xq / (dx * dq);
  const float ss = uu + qq2 + 2.0f * uq;
  const float dn = fmaxf(sqrtf(ss), EPS_NORM);
  const float es = xx / dx + xq / dq;
  const float a = 2.0f * es / (dn * dn);
  const float b = 2.0f * (xx / dx);
  const float scale = nq / dx;

  float ov[8];
#pragma unroll
  for (int k = 0; k < 8; ++k) {
    const float qp = q[k] / dq;
    const float sk = e[k] / dx + qp;
    ov[k] = (e[k] - a * sk + b * qp) * scale;
  }
  float* op = outq + (size_t)row * DD + lane * 8;
  *(float4*)op = *(const float4*)&ov[0];
  *(float4*)(op + 4) = *(const float4*)&ov[4];
  if (lane == 0) {
    outidx[row] = (float)idx;
    rloss[row] = cl;
  }
}

// ---------------- final loss reduction (deterministic) ----------------
__global__ __launch_bounds__(256) void k_loss_final(
    const float* __restrict__ rloss, float* __restrict__ out) {
  __shared__ double red[256];
  const int tid = threadIdx.x;
  double s = 0.0;
  for (int i = tid; i < TT; i += 256) s += (double)rloss[i];
  red[tid] = s;
  __syncthreads();
  for (int st = 128; st > 0; st >>= 1) {
    if (tid < st) red[tid] += red[tid + st];
    __syncthreads();
  }
  if (tid == 0) out[0] = (float)(red[0] / (double)TT);
}

extern "C" void kernel_launch(void* const* d_in, const int* in_sizes, int n_in,
                              void* d_out, int out_size, void* d_ws, size_t ws_size,
                              hipStream_t stream) {
  const float* x  = (const float*)d_in[0];   // [TT, DD]
  const float* W  = (const float*)d_in[1];   // [DD, DD]
  const float* cb = (const float*)d_in[2];   // [CC, DD]
  float* out = (float*)d_out;

  // workspace layout; xA aliases cbs (cbs dead after k_gemm_mfma)
  float* imp = (float*)d_ws;                             // CC*DD fp32 (16 MiB)
  _Float16* ihB = (_Float16*)(imp + (size_t)CC * DD);    // CC*DD f16 frag-major (8 MiB)
  _Float16* cbs = ihB + (size_t)CC * DD;                 // CC*1024 f16 (16 MiB)
  _Float16* xA = cbs;                                    // TT*DD f16 frag-major (alias)
  _Float16* Ws = cbs + (size_t)CC * 1024;                // DD*1024 f16 (1 MiB)
  float* cnorm = (float*)(Ws + (size_t)DD * 1024);       // CC
  float* bval  = cnorm + CC;                             // SPLITC*TT*2 (8 MiB)
  int*   bidx  = (int*)(bval + (size_t)SPLITC * TT * 2); // 8 MiB
  float* rloss = (float*)(bidx + (size_t)SPLITC * TT * 2);

  float* out_q    = out;
  float* out_idx  = out + (size_t)TT * DD;
  float* out_loss = out_idx + TT;

  k_split<<<CC, 128, 0, stream>>>(cb, cbs);
  k_split<<<DD, 128, 0, stream>>>(W, Ws);
  k_gemm_mfma<<<dim3(CC / 128, DD / 128), 256, 0, stream>>>(cbs, Ws, imp);
  k_row_norm2<<<CC / 4, 256, 0, stream>>>(imp, cnorm);
  k_cast_frag<<<dim3(CC / 256, 16), 256, 0, stream>>>(imp, ihB);  // codes -> frag-major
  k_cast_frag<<<dim3(TT / 256, 16), 256, 0, stream>>>(x, xA);     // x -> frag-major
  k_dist_top2<<<(TT / 128) * (CC / 128), 256, 0, stream>>>(xA, ihB, cnorm, bval, bidx);
  k_epilogue<<<TT / 4, 256, 0, stream>>>(x, imp, cnorm, bval, bidx, out_q, out_idx, rloss);
  k_loss_final<<<1, 256, 0, stream>>>(rloss, out_loss);
}